// Round 11
// baseline (461.311 us; speedup 1.0000x reference)
//
#include <hip/hip_runtime.h>
#include <hip/hip_fp16.h>

#define N_NODES 50000
#define N_EDGES 800000
#define IN_DIM 16
#define HID 16
#define EDGE_DIM 8
#define GRAPH_DIM 8
#define N_LAYERS 3
#define SCAN_BS 256
#define SCAN_NB ((N_NODES + SCAN_BS - 1) / SCAN_BS)   // 196

typedef unsigned uint4v __attribute__((ext_vector_type(4)));

__device__ __forceinline__ unsigned pack_h2(float lo, float hi) {
    __half2 h = __floats2half2_rn(lo, hi);
    return *reinterpret_cast<unsigned*>(&h);
}
__device__ __forceinline__ float2 unpack_h2(unsigned u) {
    __half2 h = *reinterpret_cast<__half2*>(&u);
    return __half22float2(h);
}

// ---------------------------------------------------------------------------
// CSR build (once per launch; edge_index is layer-invariant)
// ---------------------------------------------------------------------------
__global__ __launch_bounds__(256)
void zero_deg_kernel(int* __restrict__ deg) {
    int i = blockIdx.x * blockDim.x + threadIdx.x;
    if (i < N_NODES) deg[i] = 0;
}

__global__ __launch_bounds__(256)
void hist_kernel(const int* __restrict__ ei, int* __restrict__ deg) {
    int e = blockIdx.x * blockDim.x + threadIdx.x;
    if (e < N_EDGES) atomicAdd(&deg[ei[N_EDGES + e]], 1);
}

__global__ __launch_bounds__(SCAN_BS)
void scan1_kernel(const int* __restrict__ deg, int* __restrict__ offs,
                  int* __restrict__ bsum) {
    __shared__ int s[SCAN_BS];
    int tid = threadIdx.x;
    int i = blockIdx.x * SCAN_BS + tid;
    int v = (i < N_NODES) ? deg[i] : 0;
    s[tid] = v;
    __syncthreads();
    for (int off = 1; off < SCAN_BS; off <<= 1) {
        int t = (tid >= off) ? s[tid - off] : 0;
        __syncthreads();
        s[tid] += t;
        __syncthreads();
    }
    if (i < N_NODES) offs[i] = s[tid] - v;           // exclusive
    if (tid == SCAN_BS - 1) bsum[blockIdx.x] = s[tid];
}

__global__ __launch_bounds__(SCAN_BS)
void scan2_kernel(int* __restrict__ bsum) {
    __shared__ int s[SCAN_BS];
    int tid = threadIdx.x;
    int v = (tid < SCAN_NB) ? bsum[tid] : 0;
    s[tid] = v;
    __syncthreads();
    for (int off = 1; off < SCAN_BS; off <<= 1) {
        int t = (tid >= off) ? s[tid - off] : 0;
        __syncthreads();
        s[tid] += t;
        __syncthreads();
    }
    if (tid < SCAN_NB) bsum[tid] = s[tid] - v;
}

__global__ __launch_bounds__(SCAN_BS)
void scan3_kernel(int* __restrict__ offs, const int* __restrict__ bsum,
                  int* __restrict__ cur) {
    int i = blockIdx.x * SCAN_BS + threadIdx.x;
    if (i < N_NODES) {
        int o = offs[i] + bsum[blockIdx.x];
        offs[i] = o;
        cur[i] = o;
    }
    if (i == 0) offs[N_NODES] = N_EDGES;
}

// fill: scatter edges into CSR order (nt stores: no reuse inside this kernel)
__global__ __launch_bounds__(256)
void fill_kernel(const int* __restrict__ ei, const float* __restrict__ ea,
                 int* __restrict__ cur, int* __restrict__ csr_src,
                 uint4v* __restrict__ ea_h) {
    int e = blockIdx.x * blockDim.x + threadIdx.x;
    if (e >= N_EDGES) return;
    int src = ei[e];
    int dst = ei[N_EDGES + e];
    const float4* eap = (const float4*)(ea + (size_t)e * EDGE_DIM);
    float4 e0 = eap[0];
    float4 e1 = eap[1];
    uint4v rec;
    rec.x = pack_h2(e0.x, e0.y);
    rec.y = pack_h2(e0.z, e0.w);
    rec.z = pack_h2(e1.x, e1.y);
    rec.w = pack_h2(e1.z, e1.w);
    int j = atomicAdd(&cur[dst], 1);
    __builtin_nontemporal_store(src, &csr_src[j]);
    __builtin_nontemporal_store(rec, &ea_h[j]);
}

// ---------------------------------------------------------------------------
// prep: one thread per (node, o). fp16-packed zw (normal stores: re-read by agg)
// ---------------------------------------------------------------------------
__global__ __launch_bounds__(256)
void prep_kernel(const float* __restrict__ x_in,   // [N,16]
                 const float* __restrict__ nnW,    // [8,256]
                 const float* __restrict__ nnb,    // [256]
                 const float* __restrict__ rootW,  // [16,16]
                 const float* __restrict__ bias,   // [16]
                 unsigned* __restrict__ zw_h,      // [N,5,16] half2
                 float* __restrict__ rb,           // [N,16]
                 int apply_relu) {
    int t = blockIdx.x * blockDim.x + threadIdx.x;
    if (t >= N_NODES * HID) return;
    int n = t >> 4;
    int o = t & 15;

    float xv[IN_DIM];
    const float* xr = x_in + n * IN_DIM;
#pragma unroll
    for (int i = 0; i < IN_DIM; ++i) {
        float v = xr[i];
        xv[i] = apply_relu ? fmaxf(v, 0.0f) : v;
    }

    float zk[EDGE_DIM];
#pragma unroll
    for (int k = 0; k < EDGE_DIM; ++k) zk[k] = 0.0f;
    float wv = 0.0f;
    float rv = bias[o];

#pragma unroll
    for (int i = 0; i < IN_DIM; ++i) {
        float xi = xv[i];
#pragma unroll
        for (int k = 0; k < EDGE_DIM; ++k) {
            zk[k] = fmaf(xi, nnW[k * 256 + i * 16 + o], zk[k]);
        }
        wv = fmaf(xi, nnb[i * 16 + o], wv);
        rv = fmaf(xi, rootW[i * 16 + o], rv);
    }

    unsigned* zn = zw_h + (size_t)n * 80;
#pragma unroll
    for (int kp = 0; kp < 4; ++kp) zn[kp * 16 + o] = pack_h2(zk[2 * kp], zk[2 * kp + 1]);
    zn[64 + o] = pack_h2(wv, 0.0f);
    rb[n * 16 + o] = rv;
}

// ---------------------------------------------------------------------------
// agg: 16 lanes per node. NT loads on the sequential csr/ea streams so the
// random-gathered zw working set (16 MB, the only reused data) stays in L2.
// DO_HEAD: fuse the head MLP via width-16 shuffle reduction (last layer).
// ---------------------------------------------------------------------------
template <bool DO_HEAD>
__global__ __launch_bounds__(256)
void agg_kernel(const int* __restrict__ offs,       // [N+1]
                const int* __restrict__ csr_src,    // [E]
                const uint4v* __restrict__ ea_h,    // [E] fp16x8
                const unsigned* __restrict__ zw_h,  // [N,5,16] half2
                float* __restrict__ buf,            // in: rb, out: pre-ReLU
                const float* __restrict__ gf,       // [8,N]   (head only)
                const float* __restrict__ hW,       // [24]    (head only)
                const float* __restrict__ hb,       // [1]     (head only)
                float* __restrict__ out) {          // [N]     (head only)
    int tid = threadIdx.x;
    int o = tid & 15;
    int n = blockIdx.x * 16 + (tid >> 4);
    if (n >= N_NODES) return;

    float acc = buf[n * HID + o];
    int jb = offs[n], je = offs[n + 1];
    for (int j = jb; j < je; ++j) {
        int src = __builtin_nontemporal_load(&csr_src[j]);
        uint4v rec = __builtin_nontemporal_load(&ea_h[j]);
        const unsigned* zp = zw_h + (size_t)src * 80;
        unsigned q0 = zp[o];
        unsigned q1 = zp[16 + o];
        unsigned q2 = zp[32 + o];
        unsigned q3 = zp[48 + o];
        unsigned q4 = zp[64 + o];
        float2 e01 = unpack_h2(rec.x);
        float2 e23 = unpack_h2(rec.y);
        float2 e45 = unpack_h2(rec.z);
        float2 e67 = unpack_h2(rec.w);
        float2 z01 = unpack_h2(q0);
        float2 z23 = unpack_h2(q1);
        float2 z45 = unpack_h2(q2);
        float2 z67 = unpack_h2(q3);
        float2 w_  = unpack_h2(q4);
        acc += w_.x;
        acc = fmaf(e01.x, z01.x, acc);
        acc = fmaf(e01.y, z01.y, acc);
        acc = fmaf(e23.x, z23.x, acc);
        acc = fmaf(e23.y, z23.y, acc);
        acc = fmaf(e45.x, z45.x, acc);
        acc = fmaf(e45.y, z45.y, acc);
        acc = fmaf(e67.x, z67.x, acc);
        acc = fmaf(e67.y, z67.y, acc);
    }

    if (!DO_HEAD) {
        buf[n * HID + o] = acc;
    } else {
        // h = relu(acc)*hW[o] + (o<8 ? gf[o][n]*hW[16+o] : 0), reduce over 16 lanes
        float h = fmaxf(acc, 0.0f) * hW[o];
        if (o < GRAPH_DIM) h = fmaf(gf[o * N_NODES + n], hW[HID + o], h);
#pragma unroll
        for (int off = 8; off > 0; off >>= 1) h += __shfl_xor(h, off, 16);
        if (o == 0) out[n] = h + hb[0];
    }
}

extern "C" void kernel_launch(void* const* d_in, const int* in_sizes, int n_in,
                              void* d_out, int out_size, void* d_ws, size_t ws_size,
                              hipStream_t stream) {
    const float* x     = (const float*)d_in[0];
    const int*   ei    = (const int*)d_in[1];
    const float* ea    = (const float*)d_in[2];
    const float* gf    = (const float*)d_in[3];
    const float* nnW   = (const float*)d_in[4];
    const float* nnb   = (const float*)d_in[5];
    const float* rootW = (const float*)d_in[6];
    const float* bias  = (const float*)d_in[7];
    const float* hW    = (const float*)d_in[8];
    const float* hb    = (const float*)d_in[9];
    float* out = (float*)d_out;

    // workspace layout (~39 MB, same as the proven round-8 layout):
    unsigned* zw_h = (unsigned*)d_ws;
    uint4v* ea_h   = (uint4v*)(zw_h + (size_t)N_NODES * 80);  // 16MB offset, 16B aligned
    float* bufA    = (float*)(ea_h + N_EDGES);
    float* bufB    = bufA + (size_t)N_NODES * HID;
    int* csr_src   = (int*)(bufB + (size_t)N_NODES * HID);
    int* deg       = csr_src + N_EDGES;
    int* offs      = deg + N_NODES;
    int* cur       = offs + N_NODES + 8;
    int* bsum      = cur + N_NODES;

    dim3 blk(256);
    dim3 grid_n((N_NODES + 255) / 256);          // 196
    dim3 grid_e((N_EDGES + 255) / 256);          // 3125
    dim3 grid_no((N_NODES * HID + 255) / 256);   // 3125
    dim3 grid_a((N_NODES + 15) / 16);            // 3125 (16 nodes/block)

    // ---- CSR build (once; reused by all 3 layers) ----
    zero_deg_kernel<<<grid_n, blk, 0, stream>>>(deg);
    hist_kernel<<<grid_e, blk, 0, stream>>>(ei, deg);
    scan1_kernel<<<SCAN_NB, SCAN_BS, 0, stream>>>(deg, offs, bsum);
    scan2_kernel<<<1, SCAN_BS, 0, stream>>>(bsum);
    scan3_kernel<<<SCAN_NB, SCAN_BS, 0, stream>>>(offs, bsum, cur);
    fill_kernel<<<grid_e, blk, 0, stream>>>(ei, ea, cur, csr_src, ea_h);

    // ---- 3 NNConv layers; head fused into the last agg ----
    const float* xin = x;
    float* bufs[2] = {bufA, bufB};
    for (int l = 0; l < N_LAYERS; ++l) {
        float* buf = bufs[l & 1];
        prep_kernel<<<grid_no, blk, 0, stream>>>(
            xin,
            nnW + (size_t)l * EDGE_DIM * (IN_DIM * HID),
            nnb + (size_t)l * (IN_DIM * HID),
            rootW + (size_t)l * IN_DIM * HID,
            bias + (size_t)l * HID,
            zw_h, buf, l > 0 ? 1 : 0);
        if (l < N_LAYERS - 1) {
            agg_kernel<false><<<grid_a, blk, 0, stream>>>(
                offs, csr_src, ea_h, zw_h, buf, nullptr, nullptr, nullptr, nullptr);
        } else {
            agg_kernel<true><<<grid_a, blk, 0, stream>>>(
                offs, csr_src, ea_h, zw_h, buf, gf, hW, hb, out);
        }
        xin = buf;
    }
}

// Round 12
// 374.396 us; speedup vs baseline: 1.2321x; 1.2321x over previous
//
#include <hip/hip_runtime.h>
#include <hip/hip_fp16.h>

#define N_NODES 50000
#define N_EDGES 800000
#define IN_DIM 16
#define HID 16
#define EDGE_DIM 8
#define GRAPH_DIM 8
#define N_LAYERS 3
#define SCAN_BS 256
#define SCAN_NB ((N_NODES + SCAN_BS - 1) / SCAN_BS)   // 196

typedef unsigned uint4v __attribute__((ext_vector_type(4)));

__device__ __forceinline__ unsigned pack_h2(float lo, float hi) {
    __half2 h = __floats2half2_rn(lo, hi);
    return *reinterpret_cast<unsigned*>(&h);
}
__device__ __forceinline__ float2 unpack_h2(unsigned u) {
    __half2 h = *reinterpret_cast<__half2*>(&u);
    return __half22float2(h);
}

// ---------------------------------------------------------------------------
// CSR build (once per launch; edge_index is layer-invariant)
// deg is zeroed by hipMemsetAsync on the host side.
// ---------------------------------------------------------------------------
__global__ __launch_bounds__(256)
void hist_kernel(const int* __restrict__ ei, int* __restrict__ deg) {
    int e = blockIdx.x * blockDim.x + threadIdx.x;
    if (e < N_EDGES) atomicAdd(&deg[ei[N_EDGES + e]], 1);
}

__global__ __launch_bounds__(SCAN_BS)
void scan1_kernel(const int* __restrict__ deg, int* __restrict__ offs,
                  int* __restrict__ bsum) {
    __shared__ int s[SCAN_BS];
    int tid = threadIdx.x;
    int i = blockIdx.x * SCAN_BS + tid;
    int v = (i < N_NODES) ? deg[i] : 0;
    s[tid] = v;
    __syncthreads();
    for (int off = 1; off < SCAN_BS; off <<= 1) {
        int t = (tid >= off) ? s[tid - off] : 0;
        __syncthreads();
        s[tid] += t;
        __syncthreads();
    }
    if (i < N_NODES) offs[i] = s[tid] - v;           // exclusive
    if (tid == SCAN_BS - 1) bsum[blockIdx.x] = s[tid];
}

__global__ __launch_bounds__(SCAN_BS)
void scan2_kernel(int* __restrict__ bsum) {
    __shared__ int s[SCAN_BS];
    int tid = threadIdx.x;
    int v = (tid < SCAN_NB) ? bsum[tid] : 0;
    s[tid] = v;
    __syncthreads();
    for (int off = 1; off < SCAN_BS; off <<= 1) {
        int t = (tid >= off) ? s[tid - off] : 0;
        __syncthreads();
        s[tid] += t;
        __syncthreads();
    }
    if (tid < SCAN_NB) bsum[tid] = s[tid] - v;
}

__global__ __launch_bounds__(SCAN_BS)
void scan3_kernel(int* __restrict__ offs, const int* __restrict__ bsum,
                  int* __restrict__ cur) {
    int i = blockIdx.x * SCAN_BS + threadIdx.x;
    if (i < N_NODES) {
        int o = offs[i] + bsum[blockIdx.x];
        offs[i] = o;
        cur[i] = o;
    }
    if (i == 0) offs[N_NODES] = N_EDGES;
}

// fill: scatter edges into CSR order (plain stores — NT regressed in R11)
__global__ __launch_bounds__(256)
void fill_kernel(const int* __restrict__ ei, const float* __restrict__ ea,
                 int* __restrict__ cur, int* __restrict__ csr_src,
                 uint4v* __restrict__ ea_h) {
    int e = blockIdx.x * blockDim.x + threadIdx.x;
    if (e >= N_EDGES) return;
    int src = ei[e];
    int dst = ei[N_EDGES + e];
    const float4* eap = (const float4*)(ea + (size_t)e * EDGE_DIM);
    float4 e0 = eap[0];
    float4 e1 = eap[1];
    uint4v rec;
    rec.x = pack_h2(e0.x, e0.y);
    rec.y = pack_h2(e0.z, e0.w);
    rec.z = pack_h2(e1.x, e1.y);
    rec.w = pack_h2(e1.z, e1.w);
    int j = atomicAdd(&cur[dst], 1);
    csr_src[j] = src;
    ea_h[j] = rec;
}

// ---------------------------------------------------------------------------
// prep: one thread per (node, o). fp16-packed zw.
// ---------------------------------------------------------------------------
__global__ __launch_bounds__(256)
void prep_kernel(const float* __restrict__ x_in,   // [N,16]
                 const float* __restrict__ nnW,    // [8,256]
                 const float* __restrict__ nnb,    // [256]
                 const float* __restrict__ rootW,  // [16,16]
                 const float* __restrict__ bias,   // [16]
                 unsigned* __restrict__ zw_h,      // [N,5,16] half2
                 float* __restrict__ rb,           // [N,16]
                 int apply_relu) {
    int t = blockIdx.x * blockDim.x + threadIdx.x;
    if (t >= N_NODES * HID) return;
    int n = t >> 4;
    int o = t & 15;

    float xv[IN_DIM];
    const float* xr = x_in + n * IN_DIM;
#pragma unroll
    for (int i = 0; i < IN_DIM; ++i) {
        float v = xr[i];
        xv[i] = apply_relu ? fmaxf(v, 0.0f) : v;
    }

    float zk[EDGE_DIM];
#pragma unroll
    for (int k = 0; k < EDGE_DIM; ++k) zk[k] = 0.0f;
    float wv = 0.0f;
    float rv = bias[o];

#pragma unroll
    for (int i = 0; i < IN_DIM; ++i) {
        float xi = xv[i];
#pragma unroll
        for (int k = 0; k < EDGE_DIM; ++k) {
            zk[k] = fmaf(xi, nnW[k * 256 + i * 16 + o], zk[k]);
        }
        wv = fmaf(xi, nnb[i * 16 + o], wv);
        rv = fmaf(xi, rootW[i * 16 + o], rv);
    }

    unsigned* zn = zw_h + (size_t)n * 80;
#pragma unroll
    for (int kp = 0; kp < 4; ++kp) zn[kp * 16 + o] = pack_h2(zk[2 * kp], zk[2 * kp + 1]);
    zn[64 + o] = pack_h2(wv, 0.0f);
    rb[n * 16 + o] = rv;
}

// ---------------------------------------------------------------------------
// per-edge accumulate helper (9 fmafs into acc)
// ---------------------------------------------------------------------------
__device__ __forceinline__ void edge_accum(const unsigned* __restrict__ zp,
                                           uint4v rec, int o, float& acc) {
    unsigned q0 = zp[o];
    unsigned q1 = zp[16 + o];
    unsigned q2 = zp[32 + o];
    unsigned q3 = zp[48 + o];
    unsigned q4 = zp[64 + o];
    float2 e01 = unpack_h2(rec.x);
    float2 e23 = unpack_h2(rec.y);
    float2 e45 = unpack_h2(rec.z);
    float2 e67 = unpack_h2(rec.w);
    float2 z01 = unpack_h2(q0);
    float2 z23 = unpack_h2(q1);
    float2 z45 = unpack_h2(q2);
    float2 z67 = unpack_h2(q3);
    float2 w_  = unpack_h2(q4);
    acc += w_.x;
    acc = fmaf(e01.x, z01.x, acc);
    acc = fmaf(e01.y, z01.y, acc);
    acc = fmaf(e23.x, z23.x, acc);
    acc = fmaf(e23.y, z23.y, acc);
    acc = fmaf(e45.x, z45.x, acc);
    acc = fmaf(e45.y, z45.y, acc);
    acc = fmaf(e67.x, z67.x, acc);
    acc = fmaf(e67.y, z67.y, acc);
}

// ---------------------------------------------------------------------------
// agg: 16 lanes per node; edge loop unrolled x2 with dual accumulators to
// double memory-level parallelism (agg is latency-bound: VALUBusy 7.7%,
// 41% HBM, 16 VGPR). DO_HEAD fuses the head MLP on the last layer.
// ---------------------------------------------------------------------------
template <bool DO_HEAD>
__global__ __launch_bounds__(256)
void agg_kernel(const int* __restrict__ offs,       // [N+1]
                const int* __restrict__ csr_src,    // [E]
                const uint4v* __restrict__ ea_h,    // [E] fp16x8
                const unsigned* __restrict__ zw_h,  // [N,5,16] half2
                float* __restrict__ buf,            // in: rb, out: pre-ReLU
                const float* __restrict__ gf,       // [8,N]   (head only)
                const float* __restrict__ hW,       // [24]    (head only)
                const float* __restrict__ hb,       // [1]     (head only)
                float* __restrict__ out) {          // [N]     (head only)
    int tid = threadIdx.x;
    int o = tid & 15;
    int n = blockIdx.x * 16 + (tid >> 4);
    if (n >= N_NODES) return;

    float acc0 = buf[n * HID + o];
    float acc1 = 0.0f;
    int jb = offs[n], je = offs[n + 1];
    int j = jb;
    for (; j + 1 < je; j += 2) {
        int s0 = csr_src[j];
        int s1 = csr_src[j + 1];
        uint4v r0 = ea_h[j];
        uint4v r1 = ea_h[j + 1];
        const unsigned* zp0 = zw_h + (size_t)s0 * 80;
        const unsigned* zp1 = zw_h + (size_t)s1 * 80;
        edge_accum(zp0, r0, o, acc0);
        edge_accum(zp1, r1, o, acc1);
    }
    if (j < je) {
        int s0 = csr_src[j];
        uint4v r0 = ea_h[j];
        edge_accum(zw_h + (size_t)s0 * 80, r0, o, acc0);
    }
    float acc = acc0 + acc1;

    if (!DO_HEAD) {
        buf[n * HID + o] = acc;
    } else {
        // h = relu(acc)*hW[o] + (o<8 ? gf[o][n]*hW[16+o] : 0), reduce 16 lanes
        float h = fmaxf(acc, 0.0f) * hW[o];
        if (o < GRAPH_DIM) h = fmaf(gf[o * N_NODES + n], hW[HID + o], h);
#pragma unroll
        for (int off = 8; off > 0; off >>= 1) h += __shfl_xor(h, off, 16);
        if (o == 0) out[n] = h + hb[0];
    }
}

extern "C" void kernel_launch(void* const* d_in, const int* in_sizes, int n_in,
                              void* d_out, int out_size, void* d_ws, size_t ws_size,
                              hipStream_t stream) {
    const float* x     = (const float*)d_in[0];
    const int*   ei    = (const int*)d_in[1];
    const float* ea    = (const float*)d_in[2];
    const float* gf    = (const float*)d_in[3];
    const float* nnW   = (const float*)d_in[4];
    const float* nnb   = (const float*)d_in[5];
    const float* rootW = (const float*)d_in[6];
    const float* bias  = (const float*)d_in[7];
    const float* hW    = (const float*)d_in[8];
    const float* hb    = (const float*)d_in[9];
    float* out = (float*)d_out;

    // workspace layout (~39 MB, proven round-8 layout):
    unsigned* zw_h = (unsigned*)d_ws;
    uint4v* ea_h   = (uint4v*)(zw_h + (size_t)N_NODES * 80);  // 16MB offset, 16B aligned
    float* bufA    = (float*)(ea_h + N_EDGES);
    float* bufB    = bufA + (size_t)N_NODES * HID;
    int* csr_src   = (int*)(bufB + (size_t)N_NODES * HID);
    int* deg       = csr_src + N_EDGES;
    int* offs      = deg + N_NODES;
    int* cur       = offs + N_NODES + 8;
    int* bsum      = cur + N_NODES;

    dim3 blk(256);
    dim3 grid_e((N_EDGES + 255) / 256);          // 3125
    dim3 grid_no((N_NODES * HID + 255) / 256);   // 3125
    dim3 grid_a((N_NODES + 15) / 16);            // 3125 (16 nodes/block)

    // ---- CSR build (once; reused by all 3 layers) ----
    hipMemsetAsync(deg, 0, N_NODES * sizeof(int), stream);
    hist_kernel<<<grid_e, blk, 0, stream>>>(ei, deg);
    scan1_kernel<<<SCAN_NB, SCAN_BS, 0, stream>>>(deg, offs, bsum);
    scan2_kernel<<<1, SCAN_BS, 0, stream>>>(bsum);
    scan3_kernel<<<SCAN_NB, SCAN_BS, 0, stream>>>(offs, bsum, cur);
    fill_kernel<<<grid_e, blk, 0, stream>>>(ei, ea, cur, csr_src, ea_h);

    // ---- 3 NNConv layers; head fused into the last agg ----
    const float* xin = x;
    float* bufs[2] = {bufA, bufB};
    for (int l = 0; l < N_LAYERS; ++l) {
        float* buf = bufs[l & 1];
        prep_kernel<<<grid_no, blk, 0, stream>>>(
            xin,
            nnW + (size_t)l * EDGE_DIM * (IN_DIM * HID),
            nnb + (size_t)l * (IN_DIM * HID),
            rootW + (size_t)l * IN_DIM * HID,
            bias + (size_t)l * HID,
            zw_h, buf, l > 0 ? 1 : 0);
        if (l < N_LAYERS - 1) {
            agg_kernel<false><<<grid_a, blk, 0, stream>>>(
                offs, csr_src, ea_h, zw_h, buf, nullptr, nullptr, nullptr, nullptr);
        } else {
            agg_kernel<true><<<grid_a, blk, 0, stream>>>(
                offs, csr_src, ea_h, zw_h, buf, gf, hW, hb, out);
        }
        xin = buf;
    }
}